// Round 16
// baseline (359.366 us; speedup 1.0000x reference)
//
#include <hip/hip_runtime.h>

#define NN 40960
#define NE 655360
#define ET (NE + NN)        // 696320 edges incl self-loops
#define D 128
#define NG 16
#define PL 33280            // params per layer: WF[32768], bf[256], att[128], b[128]

typedef unsigned int u32;
typedef unsigned short u16;
typedef long long i64;

struct P18 { const void* p[18]; };

__device__ __forceinline__ float bf2f(u16 v){ return __uint_as_float(((u32)v)<<16); }
__device__ __forceinline__ u16 f2bf(float f){
  u32 u = __float_as_uint(f);
  return (u16)((u + 0x7FFFu + ((u>>16)&1u)) >> 16);
}
__device__ __forceinline__ int geti(const void* p, long long i, int f64, int bound){
  long long v = f64 ? ((const i64*)p)[i] : (long long)((const int*)p)[i];
  int x = (int)v;
  return (x < 0) ? 0 : ((x >= bound) ? bound-1 : x);
}
__device__ __forceinline__ void stf(void* p, long long i, float v, int isbf){
  if (isbf) ((u16*)p)[i] = f2bf(v); else ((float*)p)[i] = v;
}
__device__ __forceinline__ float rdf(const void* p, int i, int isbf){
  return isbf ? bf2f(((const u16*)p)[i]) : ((const float*)p)[i];
}
// load 4 consecutive floats (element offset foff, multiple of 4) from f32 or bf16 buffer
__device__ __forceinline__ float4 ld4(const void* p, size_t foff, int isbf){
  if (!isbf) return *(const float4*)((const float*)p + foff);
  ushort4 u = *(const ushort4*)((const u16*)p + foff);
  return make_float4(bf2f(u.x), bf2f(u.y), bf2f(u.z), bf2f(u.w));
}
// bf16x4 load (8 B) -> 4 floats
__device__ __forceinline__ float4 ldb4(const u16* p){
  ushort4 u = *(const ushort4*)p;
  return make_float4(bf2f(u.x), bf2f(u.y), bf2f(u.z), bf2f(u.w));
}

// block 0: dtype detect; blocks 1..160: zero cursor; blocks 161..168: zero pool
__global__ void k_setup(const void* __restrict__ ei, const void* __restrict__ x,
                        int* __restrict__ flags, u32* __restrict__ cursor, float* __restrict__ pool){
  int b = blockIdx.x;
  if (b == 0){
    __shared__ int nz, cnt;
    if (threadIdx.x == 0){ nz = 0; cnt = 0; }
    __syncthreads();
    if (((const int*)ei)[2*threadIdx.x + 1] != 0) atomicAdd(&nz, 1);
    if (threadIdx.x < 128){
      u16 v = ((const u16*)x)[2*threadIdx.x];
      int ex = (v >> 7) & 0xFF;
      if (ex >= 100 && ex <= 140) atomicAdd(&cnt, 1);
    }
    __syncthreads();
    if (threadIdx.x == 0){
      flags[0] = (nz == 0) ? 1 : 0;
      flags[1] = (cnt >= 64) ? 1 : 0;
    }
  } else if (b <= 160){
    cursor[(b-1)*256 + threadIdx.x] = 0u;
  } else {
    int i = (b-161)*256 + threadIdx.x;
    if (i < NG*D) pool[i] = 0.f;
  }
}

// param pack only (130 blocks/layer)
__global__ void k_prep(P18 ps, float* __restrict__ prm, const int* __restrict__ flags){
  int b = blockIdx.x;
  int l = b / 130;
  int i = (b % 130)*256 + threadIdx.x;
  const void* Wl  = ps.p[6*l+0];
  const void* bl  = ps.p[6*l+1];
  const void* Wr  = ps.p[6*l+2];
  const void* br  = ps.p[6*l+3];
  const void* att = ps.p[6*l+4];
  const void* bb  = ps.p[6*l+5];
  int isbf = flags[1];
  float v;
  if (i < 32768){
    int k = i >> 8, gc = i & 255;
    v = (gc < 128) ? rdf(Wl, k*128 + gc, isbf) : rdf(Wr, k*128 + gc - 128, isbf);
  }
  else if (i < 33024){ int gc = i - 32768; v = (gc < 128) ? rdf(bl, gc, isbf) : rdf(br, gc - 128, isbf); }
  else if (i < 33152) v = rdf(att, i - 33024, isbf);
  else                v = rdf(bb, i - 33152, isbf);
  prm[(size_t)l*PL + i] = v;
}

// ---------- CSR build (by dst, self-loops appended); entry packs src|dst<<16 ----------
__global__ void k_hist(const void* __restrict__ ei, u32* __restrict__ cursor, const int* __restrict__ flags){
  int e = blockIdx.x*256 + threadIdx.x;
  if (e >= ET) return;
  int dd = (e < NE) ? geti(ei, (long long)NE + e, flags[0], NN) : e - NE;
  atomicAdd(&cursor[dd], 1u);
}

// 160 blocks: per-block sum of 256 cursor entries
__global__ __launch_bounds__(256) void k_scanA(const u32* __restrict__ cursor, u32* __restrict__ psum){
  __shared__ u32 red[256];
  int t = threadIdx.x;
  red[t] = cursor[blockIdx.x*256 + t];
  __syncthreads();
  #pragma unroll
  for (int off = 128; off > 0; off >>= 1){
    if (t < off) red[t] += red[t + off];
    __syncthreads();
  }
  if (t == 0) psum[blockIdx.x] = red[0];
}

// 1 block: exclusive scan of 160 partials (LDS), offs[NN]=total, graph bounds
__global__ __launch_bounds__(256) void k_scanB(u32* __restrict__ psum, u32* __restrict__ offs,
                                               const void* __restrict__ batch, u32* __restrict__ bnd,
                                               const int* __restrict__ flags){
  __shared__ u32 sh[256];
  int t = threadIdx.x;
  sh[t] = (t < 160) ? psum[t] : 0u;
  __syncthreads();
  #pragma unroll
  for (int off = 1; off < 256; off <<= 1){
    u32 add = (t >= off) ? sh[t - off] : 0u;
    __syncthreads();
    sh[t] += add;
    __syncthreads();
  }
  if (t < 160) psum[t] = (t == 0) ? 0u : sh[t - 1];
  if (t == 160) offs[NN] = sh[159];
  if (t >= 192 && t <= 192 + NG){
    int g = t - 192;
    if (g == NG){ bnd[NG] = NN; }
    else {
      int f = flags[0];
      int lo = 0, hi = NN;
      while (lo < hi){
        int mid = (lo + hi) >> 1;
        if (geti(batch, mid, f, NG) < g) lo = mid + 1; else hi = mid;
      }
      bnd[g] = (u32)lo;
    }
  }
}

// 160 blocks: local exclusive scan + base -> offs, cursor
__global__ __launch_bounds__(256) void k_scanC(u32* __restrict__ cursor, u32* __restrict__ offs,
                                               const u32* __restrict__ psum){
  __shared__ u32 sh[256];
  int t = threadIdx.x;
  int gi = blockIdx.x*256 + t;
  u32 v = cursor[gi];
  sh[t] = v;
  __syncthreads();
  #pragma unroll
  for (int off = 1; off < 256; off <<= 1){
    u32 add = (t >= off) ? sh[t - off] : 0u;
    __syncthreads();
    sh[t] += add;
    __syncthreads();
  }
  u32 excl = ((t > 0) ? sh[t - 1] : 0u) + psum[blockIdx.x];
  offs[gi] = excl;
  cursor[gi] = excl;
}

__global__ void k_scatter(const void* __restrict__ ei, u32* __restrict__ cursor,
                          u32* __restrict__ csr, const int* __restrict__ flags){
  int e = blockIdx.x*256 + threadIdx.x;
  if (e >= ET) return;
  int f = flags[0];
  int s, dd;
  if (e < NE){ s = geti(ei, e, f, NN); dd = geti(ei, (long long)NE + e, f, NN); }
  else { s = dd = e - NE; }
  u32 pos = atomicAdd(&cursor[dd], 1u);
  csr[pos] = (u32)s | ((u32)dd << 16);
}

// ---------- GEMM: 128x128 tile, BK=32 x 4, 8x8 quadrant microtile, reg-double-buffered ----------
// Next kt's global loads issue into registers before computing current kt (R13-proven).
// Per k: 64 FMA vs 4 ds_read_b128. LDS 32KB; bf16 output.
__global__ __launch_bounds__(256, 4) void k_gemm(const void* __restrict__ Xv, const float* __restrict__ pr,
                                                 u16* __restrict__ xl, u16* __restrict__ xr,
                                                 const int* __restrict__ flags, int lay0)
{
  __shared__ float Xs[32][128];   // [k][row], row XOR-swizzled
  __shared__ float Ws[32][128];   // [k][col]
  int tid = threadIdx.x;
  int row0 = blockIdx.x * 128;
  int bc0  = blockIdx.y * 128;    // 0 -> xl, 128 -> xr
  int ty = tid >> 4, tx = tid & 15;
  int r = ty*4, c = tx*4;
  int isbf = lay0 ? flags[1] : 0;

  float4 bv0 = *(const float4*)(pr + 32768 + bc0 + c);
  float4 bv1 = *(const float4*)(pr + 32768 + bc0 + c + 64);
  float acc[2][2][4][4];
  #pragma unroll
  for (int qr = 0; qr < 2; ++qr)
    #pragma unroll
    for (int i = 0; i < 4; ++i){
      acc[qr][0][i][0] = bv0.x; acc[qr][0][i][1] = bv0.y;
      acc[qr][0][i][2] = bv0.z; acc[qr][0][i][3] = bv0.w;
      acc[qr][1][i][0] = bv1.x; acc[qr][1][i][1] = bv1.y;
      acc[qr][1][i][2] = bv1.z; acc[qr][1][i][3] = bv1.w;
    }

  // staging registers + fixed per-thread addressing
  float4 xv[4], wv[4];
  int xrow[4], xk4[4];
  #pragma unroll
  for (int i = 0; i < 4; ++i){
    int idx = tid + i*256;
    xrow[i] = idx >> 3;           // 0..127
    xk4[i]  = idx & 7;            // float4 slot in 32-k row
  }
  // W addressing: idx = tid + i*256 -> k = idx>>5 (0..31), c4 = idx&31

  // prologue: load kt=0
  #pragma unroll
  for (int i = 0; i < 4; ++i)
    xv[i] = ld4(Xv, (size_t)(row0 + xrow[i])*D + 0 + xk4[i]*4, isbf);
  #pragma unroll
  for (int i = 0; i < 4; ++i){
    int idx = tid + i*256;
    int k = idx >> 5, c4 = idx & 31;
    wv[i] = *(const float4*)(pr + (size_t)k*256 + bc0 + c4*4);
  }

  #pragma unroll
  for (int kt = 0; kt < 4; ++kt){
    __syncthreads();               // previous compute done reading LDS
    #pragma unroll
    for (int i = 0; i < 4; ++i){
      int rs = xrow[i] ^ (xk4[i] << 2);
      Xs[xk4[i]*4+0][rs] = xv[i].x;
      Xs[xk4[i]*4+1][rs] = xv[i].y;
      Xs[xk4[i]*4+2][rs] = xv[i].z;
      Xs[xk4[i]*4+3][rs] = xv[i].w;
    }
    #pragma unroll
    for (int i = 0; i < 4; ++i){
      int idx = tid + i*256;
      int k = idx >> 5, c4 = idx & 31;
      *(float4*)&Ws[k][c4*4] = wv[i];
    }
    __syncthreads();
    if (kt < 3){                   // issue next tile's loads under compute
      #pragma unroll
      for (int i = 0; i < 4; ++i)
        xv[i] = ld4(Xv, (size_t)(row0 + xrow[i])*D + (kt+1)*32 + xk4[i]*4, isbf);
      #pragma unroll
      for (int i = 0; i < 4; ++i){
        int idx = tid + i*256;
        int k = idx >> 5, c4 = idx & 31;
        wv[i] = *(const float4*)(pr + (size_t)((kt+1)*32 + k)*256 + bc0 + c4*4);
      }
    }
    #pragma unroll 4
    for (int k = 0; k < 32; ++k){
      int swb = ((k >> 2) & 7) << 2;
      int ra = r ^ swb;
      float4 a0 = *(const float4*)&Xs[k][ra];
      float4 a1 = *(const float4*)&Xs[k][ra + 64];
      float4 w0 = *(const float4*)&Ws[k][c];
      float4 w1 = *(const float4*)&Ws[k][c + 64];
      #pragma unroll
      for (int qr = 0; qr < 2; ++qr){
        float ax = qr ? a1.x : a0.x, ay = qr ? a1.y : a0.y;
        float az = qr ? a1.z : a0.z, aw = qr ? a1.w : a0.w;
        #pragma unroll
        for (int qc = 0; qc < 2; ++qc){
          float wx = qc ? w1.x : w0.x, wy = qc ? w1.y : w0.y;
          float wz = qc ? w1.z : w0.z, ww = qc ? w1.w : w0.w;
          acc[qr][qc][0][0] = fmaf(ax, wx, acc[qr][qc][0][0]);
          acc[qr][qc][0][1] = fmaf(ax, wy, acc[qr][qc][0][1]);
          acc[qr][qc][0][2] = fmaf(ax, wz, acc[qr][qc][0][2]);
          acc[qr][qc][0][3] = fmaf(ax, ww, acc[qr][qc][0][3]);
          acc[qr][qc][1][0] = fmaf(ay, wx, acc[qr][qc][1][0]);
          acc[qr][qc][1][1] = fmaf(ay, wy, acc[qr][qc][1][1]);
          acc[qr][qc][1][2] = fmaf(ay, wz, acc[qr][qc][1][2]);
          acc[qr][qc][1][3] = fmaf(ay, ww, acc[qr][qc][1][3]);
          acc[qr][qc][2][0] = fmaf(az, wx, acc[qr][qc][2][0]);
          acc[qr][qc][2][1] = fmaf(az, wy, acc[qr][qc][2][1]);
          acc[qr][qc][2][2] = fmaf(az, wz, acc[qr][qc][2][2]);
          acc[qr][qc][2][3] = fmaf(az, ww, acc[qr][qc][2][3]);
          acc[qr][qc][3][0] = fmaf(aw, wx, acc[qr][qc][3][0]);
          acc[qr][qc][3][1] = fmaf(aw, wy, acc[qr][qc][3][1]);
          acc[qr][qc][3][2] = fmaf(aw, wz, acc[qr][qc][3][2]);
          acc[qr][qc][3][3] = fmaf(aw, ww, acc[qr][qc][3][3]);
        }
      }
    }
  }

  u16* base = bc0 ? xr : xl;
  #pragma unroll
  for (int qr = 0; qr < 2; ++qr)
    #pragma unroll
    for (int i = 0; i < 4; ++i){
      int grow = row0 + qr*64 + r + i;
      ushort4 o0 = make_ushort4(f2bf(acc[qr][0][i][0]), f2bf(acc[qr][0][i][1]),
                                f2bf(acc[qr][0][i][2]), f2bf(acc[qr][0][i][3]));
      ushort4 o1 = make_ushort4(f2bf(acc[qr][1][i][0]), f2bf(acc[qr][1][i][1]),
                                f2bf(acc[qr][1][i][2]), f2bf(acc[qr][1][i][3]));
      *(ushort4*)(base + (size_t)grow*D + c) = o0;
      *(ushort4*)(base + (size_t)grow*D + c + 64) = o1;
    }
}

// ---------- fused per-node attention: bf16 gather, depth-2 pipeline, defer-max ----------
__global__ __launch_bounds__(256) void k_node(const u16* __restrict__ xl, const u16* __restrict__ xr,
    const u32* __restrict__ offs, const u32* __restrict__ csr, const float* __restrict__ pr,
    float* __restrict__ hnew, void* __restrict__ out, const int* __restrict__ flags, int last)
{
  int node = blockIdx.x*4 + (threadIdx.x >> 6);
  int lane = threadIdx.x & 63;
  int half = lane >> 5;
  int c = (lane & 31) * 4;
  float4 xrv  = ldb4(xr + (size_t)node*D + c);
  float4 attv = *(const float4*)(pr + 33024 + c);
  u32 j0 = offs[node], j1 = offs[node + 1];

  float mx = -1e30f, ssum = 0.f;
  float4 acc = make_float4(0.f, 0.f, 0.f, 0.f);

  #define SRCJ(jj) ((int)(csr[(jj) < j1 ? (jj) : j0] & 0xFFFFu))
  u32 j = j0 + half;
  int s0 = SRCJ(j), s1 = SRCJ(j+2);
  float4 g0 = ldb4(xl + (size_t)s0*D + c);
  float4 g1 = ldb4(xl + (size_t)s1*D + c);
  int s2 = SRCJ(j+4), s3 = SRCJ(j+6);

  for (; j < j1; j += 4){
    float4 n0 = ldb4(xl + (size_t)s2*D + c);
    float4 n1 = ldb4(xl + (size_t)s3*D + c);
    int t0 = SRCJ(j+8), t1 = SRCJ(j+10);

    {
      float m, p;
      m = g0.x + xrv.x; p = fmaxf(m, 0.2f*m) * attv.x;
      m = g0.y + xrv.y; p = fmaf(fmaxf(m, 0.2f*m), attv.y, p);
      m = g0.z + xrv.z; p = fmaf(fmaxf(m, 0.2f*m), attv.z, p);
      m = g0.w + xrv.w; p = fmaf(fmaxf(m, 0.2f*m), attv.w, p);
      p += __shfl_xor(p, 1, 64);
      p += __shfl_xor(p, 2, 64);
      p += __shfl_xor(p, 4, 64);
      if (p > mx + 8.f){
        float eo = __expf(mx - p);
        ssum  *= eo;
        acc.x *= eo; acc.y *= eo; acc.z *= eo; acc.w *= eo;
        mx = p;
      }
      float en = __expf(p - mx);
      ssum += en;
      acc.x = fmaf(en, g0.x, acc.x);
      acc.y = fmaf(en, g0.y, acc.y);
      acc.z = fmaf(en, g0.z, acc.z);
      acc.w = fmaf(en, g0.w, acc.w);
    }
    if (j + 2 < j1){
      float m, p;
      m = g1.x + xrv.x; p = fmaxf(m, 0.2f*m) * attv.x;
      m = g1.y + xrv.y; p = fmaf(fmaxf(m, 0.2f*m), attv.y, p);
      m = g1.z + xrv.z; p = fmaf(fmaxf(m, 0.2f*m), attv.z, p);
      m = g1.w + xrv.w; p = fmaf(fmaxf(m, 0.2f*m), attv.w, p);
      p += __shfl_xor(p, 1, 64);
      p += __shfl_xor(p, 2, 64);
      p += __shfl_xor(p, 4, 64);
      if (p > mx + 8.f){
        float eo = __expf(mx - p);
        ssum  *= eo;
        acc.x *= eo; acc.y *= eo; acc.z *= eo; acc.w *= eo;
        mx = p;
      }
      float en = __expf(p - mx);
      ssum += en;
      acc.x = fmaf(en, g1.x, acc.x);
      acc.y = fmaf(en, g1.y, acc.y);
      acc.z = fmaf(en, g1.z, acc.z);
      acc.w = fmaf(en, g1.w, acc.w);
    }
    g0 = n0; g1 = n1; s2 = t0; s3 = t1;
  }
  #undef SRCJ

  float mo = __shfl_xor(mx, 32, 64);
  float so = __shfl_xor(ssum, 32, 64);
  float ax = __shfl_xor(acc.x, 32, 64);
  float ay = __shfl_xor(acc.y, 32, 64);
  float az = __shfl_xor(acc.z, 32, 64);
  float aw = __shfl_xor(acc.w, 32, 64);
  float n  = fmaxf(mx, mo);
  float e0 = __expf(mx - n), e1 = __expf(mo - n);
  ssum  = ssum*e0 + so*e1;
  acc.x = acc.x*e0 + ax*e1;
  acc.y = acc.y*e0 + ay*e1;
  acc.z = acc.z*e0 + az*e1;
  acc.w = acc.w*e0 + aw*e1;

  if (half == 0){
    float inv = 1.0f / fmaxf(ssum, 1e-30f);
    float4 bv = *(const float4*)(pr + 33152 + c);
    float4 v = make_float4(acc.x*inv + bv.x, acc.y*inv + bv.y,
                           acc.z*inv + bv.z, acc.w*inv + bv.w);
    if (!last){
      v.x = fmaxf(v.x, 0.f); v.y = fmaxf(v.y, 0.f);
      v.z = fmaxf(v.z, 0.f); v.w = fmaxf(v.w, 0.f);
      *(float4*)(hnew + (size_t)node*D + c) = v;
    } else {
      *(float4*)(hnew + (size_t)node*D + c) = v;
      int isbf = flags[1];
      long long o = (long long)NG*D + (long long)node*D + c;
      stf(out, o+0, v.x, isbf); stf(out, o+1, v.y, isbf);
      stf(out, o+2, v.z, isbf); stf(out, o+3, v.w, isbf);
    }
  }
}

// ---------- two-stage mean pool ----------
__global__ __launch_bounds__(256) void k_pool1(const float* __restrict__ h, const u32* __restrict__ bnd,
                                               float* __restrict__ pool){
  int g = blockIdx.x >> 6, sl = blockIdx.x & 63;
  int ch = threadIdx.x & 127, ro = threadIdx.x >> 7;
  u32 b0 = bnd[g], b1 = bnd[g + 1];
  float acc = 0.f;
  for (u32 r = b0 + sl*2 + ro; r < b1; r += 128) acc += h[(size_t)r*D + ch];
  unsafeAtomicAdd(&pool[g*D + ch], acc);
}

__global__ void k_pool2(const float* __restrict__ pool, const u32* __restrict__ bnd,
                        void* __restrict__ out, const int* __restrict__ flags){
  int i = blockIdx.x*256 + threadIdx.x;
  if (i >= NG*D) return;
  int g = i >> 7;
  float c = (float)(bnd[g + 1] - bnd[g]);
  stf(out, i, pool[i] / fmaxf(c, 1.f), flags[1]);
}

extern "C" void kernel_launch(void* const* d_in, const int* in_sizes, int n_in,
                              void* d_out, int out_size, void* d_ws, size_t ws_size,
                              hipStream_t stream) {
  const void* x     = d_in[0];
  const void* ei    = d_in[1];
  const void* batch = d_in[2];

  const long long nf = (long long)NN*D*3 + 3*PL + NG*D;
  const long long nu = (NN + 1) + NN + ET + (NG + 1) + 2 + 160;
  if (ws_size < (size_t)(nf + nu)*4 + 256) return;

  float* ws    = (float*)d_ws;
  float* xf    = ws;                               // NN*D f32 (h buffer each layer)
  u16*  xl    = (u16*)(xf + (size_t)NN*D);         // NN*D bf16
  u16*  xr    = (u16*)(xf + (size_t)NN*D*2);       // NN*D bf16
  float* prm   = xf + (size_t)NN*D*3;              // 3*PL
  float* pool  = prm + 3*PL;                       // NG*D
  u32*  offs   = (u32*)(pool + NG*D);              // NN+1
  u32*  cursor = offs + (NN + 1);                  // NN
  u32*  csr    = cursor + NN;                      // ET
  u32*  bnd    = csr + ET;                         // NG+1
  u32*  psum   = bnd + (NG + 1);                   // 160
  int*  flags  = (int*)(psum + 160);               // 2

  k_setup<<<169, 256, 0, stream>>>(ei, x, flags, cursor, pool);
  P18 ps;
  for (int i = 0; i < 18; ++i) ps.p[i] = d_in[3 + i];
  k_prep<<<390, 256, 0, stream>>>(ps, prm, flags);

  k_hist<<<ET/256, 256, 0, stream>>>(ei, cursor, flags);
  k_scanA<<<160, 256, 0, stream>>>(cursor, psum);
  k_scanB<<<1, 256, 0, stream>>>(psum, offs, batch, bnd, flags);
  k_scanC<<<160, 256, 0, stream>>>(cursor, offs, psum);
  k_scatter<<<ET/256, 256, 0, stream>>>(ei, cursor, csr, flags);

  for (int l = 0; l < 3; ++l){
    const float* p = prm + (size_t)l*PL;
    const void* Xin = (l == 0) ? x : (const void*)xf;
    k_gemm<<<dim3(NN/128, 2), 256, 0, stream>>>(Xin, p, xl, xr, flags, l == 0);
    k_node<<<NN/4, 256, 0, stream>>>(xl, xr, offs, csr, p, xf, d_out, flags, l == 2);
  }
  k_pool1<<<NG*64, 256, 0, stream>>>(xf, bnd, pool);
  k_pool2<<<8, 256, 0, stream>>>(pool, bnd, d_out, flags);
}

// Round 17
// 353.252 us; speedup vs baseline: 1.0173x; 1.0173x over previous
//
#include <hip/hip_runtime.h>

#define NN 40960
#define NE 655360
#define ET (NE + NN)        // 696320 edges incl self-loops
#define D 128
#define NG 16
#define PL 33280            // params per layer: WF[32768], bf[256], att[128], b[128]

typedef unsigned int u32;
typedef unsigned short u16;
typedef long long i64;

struct P18 { const void* p[18]; };

__device__ __forceinline__ float bf2f(u16 v){ return __uint_as_float(((u32)v)<<16); }
__device__ __forceinline__ u16 f2bf(float f){
  u32 u = __float_as_uint(f);
  return (u16)((u + 0x7FFFu + ((u>>16)&1u)) >> 16);
}
__device__ __forceinline__ int geti(const void* p, long long i, int f64, int bound){
  long long v = f64 ? ((const i64*)p)[i] : (long long)((const int*)p)[i];
  int x = (int)v;
  return (x < 0) ? 0 : ((x >= bound) ? bound-1 : x);
}
__device__ __forceinline__ void stf(void* p, long long i, float v, int isbf){
  if (isbf) ((u16*)p)[i] = f2bf(v); else ((float*)p)[i] = v;
}
__device__ __forceinline__ float rdf(const void* p, int i, int isbf){
  return isbf ? bf2f(((const u16*)p)[i]) : ((const float*)p)[i];
}
// load 4 consecutive floats (element offset foff, multiple of 4) from f32 or bf16 buffer
__device__ __forceinline__ float4 ld4(const void* p, size_t foff, int isbf){
  if (!isbf) return *(const float4*)((const float*)p + foff);
  ushort4 u = *(const ushort4*)((const u16*)p + foff);
  return make_float4(bf2f(u.x), bf2f(u.y), bf2f(u.z), bf2f(u.w));
}
// bf16x4 load (8 B) -> 4 floats
__device__ __forceinline__ float4 ldb4(const u16* p){
  ushort4 u = *(const ushort4*)p;
  return make_float4(bf2f(u.x), bf2f(u.y), bf2f(u.z), bf2f(u.w));
}

// block 0: dtype detect; blocks 1..160: zero cursor; blocks 161..168: zero pool
__global__ void k_setup(const void* __restrict__ ei, const void* __restrict__ x,
                        int* __restrict__ flags, u32* __restrict__ cursor, float* __restrict__ pool){
  int b = blockIdx.x;
  if (b == 0){
    __shared__ int nz, cnt;
    if (threadIdx.x == 0){ nz = 0; cnt = 0; }
    __syncthreads();
    if (((const int*)ei)[2*threadIdx.x + 1] != 0) atomicAdd(&nz, 1);
    if (threadIdx.x < 128){
      u16 v = ((const u16*)x)[2*threadIdx.x];
      int ex = (v >> 7) & 0xFF;
      if (ex >= 100 && ex <= 140) atomicAdd(&cnt, 1);
    }
    __syncthreads();
    if (threadIdx.x == 0){
      flags[0] = (nz == 0) ? 1 : 0;
      flags[1] = (cnt >= 64) ? 1 : 0;
    }
  } else if (b <= 160){
    cursor[(b-1)*256 + threadIdx.x] = 0u;
  } else {
    int i = (b-161)*256 + threadIdx.x;
    if (i < NG*D) pool[i] = 0.f;
  }
}

// param pack only (130 blocks/layer)
__global__ void k_prep(P18 ps, float* __restrict__ prm, const int* __restrict__ flags){
  int b = blockIdx.x;
  int l = b / 130;
  int i = (b % 130)*256 + threadIdx.x;
  const void* Wl  = ps.p[6*l+0];
  const void* bl  = ps.p[6*l+1];
  const void* Wr  = ps.p[6*l+2];
  const void* br  = ps.p[6*l+3];
  const void* att = ps.p[6*l+4];
  const void* bb  = ps.p[6*l+5];
  int isbf = flags[1];
  float v;
  if (i < 32768){
    int k = i >> 8, gc = i & 255;
    v = (gc < 128) ? rdf(Wl, k*128 + gc, isbf) : rdf(Wr, k*128 + gc - 128, isbf);
  }
  else if (i < 33024){ int gc = i - 32768; v = (gc < 128) ? rdf(bl, gc, isbf) : rdf(br, gc - 128, isbf); }
  else if (i < 33152) v = rdf(att, i - 33024, isbf);
  else                v = rdf(bb, i - 33152, isbf);
  prm[(size_t)l*PL + i] = v;
}

// ---------- CSR build (by dst, self-loops appended); entry packs src|dst<<16 ----------
__global__ void k_hist(const void* __restrict__ ei, u32* __restrict__ cursor, const int* __restrict__ flags){
  int e = blockIdx.x*256 + threadIdx.x;
  if (e >= ET) return;
  int dd = (e < NE) ? geti(ei, (long long)NE + e, flags[0], NN) : e - NE;
  atomicAdd(&cursor[dd], 1u);
}

// 160 blocks: per-block sum of 256 cursor entries
__global__ __launch_bounds__(256) void k_scanA(const u32* __restrict__ cursor, u32* __restrict__ psum){
  __shared__ u32 red[256];
  int t = threadIdx.x;
  red[t] = cursor[blockIdx.x*256 + t];
  __syncthreads();
  #pragma unroll
  for (int off = 128; off > 0; off >>= 1){
    if (t < off) red[t] += red[t + off];
    __syncthreads();
  }
  if (t == 0) psum[blockIdx.x] = red[0];
}

// 1 block: exclusive scan of 160 partials (LDS), offs[NN]=total, graph bounds
__global__ __launch_bounds__(256) void k_scanB(u32* __restrict__ psum, u32* __restrict__ offs,
                                               const void* __restrict__ batch, u32* __restrict__ bnd,
                                               const int* __restrict__ flags){
  __shared__ u32 sh[256];
  int t = threadIdx.x;
  sh[t] = (t < 160) ? psum[t] : 0u;
  __syncthreads();
  #pragma unroll
  for (int off = 1; off < 256; off <<= 1){
    u32 add = (t >= off) ? sh[t - off] : 0u;
    __syncthreads();
    sh[t] += add;
    __syncthreads();
  }
  if (t < 160) psum[t] = (t == 0) ? 0u : sh[t - 1];
  if (t == 160) offs[NN] = sh[159];
  if (t >= 192 && t <= 192 + NG){
    int g = t - 192;
    if (g == NG){ bnd[NG] = NN; }
    else {
      int f = flags[0];
      int lo = 0, hi = NN;
      while (lo < hi){
        int mid = (lo + hi) >> 1;
        if (geti(batch, mid, f, NG) < g) lo = mid + 1; else hi = mid;
      }
      bnd[g] = (u32)lo;
    }
  }
}

// 160 blocks: local exclusive scan + base -> offs, cursor
__global__ __launch_bounds__(256) void k_scanC(u32* __restrict__ cursor, u32* __restrict__ offs,
                                               const u32* __restrict__ psum){
  __shared__ u32 sh[256];
  int t = threadIdx.x;
  int gi = blockIdx.x*256 + t;
  u32 v = cursor[gi];
  sh[t] = v;
  __syncthreads();
  #pragma unroll
  for (int off = 1; off < 256; off <<= 1){
    u32 add = (t >= off) ? sh[t - off] : 0u;
    __syncthreads();
    sh[t] += add;
    __syncthreads();
  }
  u32 excl = ((t > 0) ? sh[t - 1] : 0u) + psum[blockIdx.x];
  offs[gi] = excl;
  cursor[gi] = excl;
}

__global__ void k_scatter(const void* __restrict__ ei, u32* __restrict__ cursor,
                          u32* __restrict__ csr, const int* __restrict__ flags){
  int e = blockIdx.x*256 + threadIdx.x;
  if (e >= ET) return;
  int f = flags[0];
  int s, dd;
  if (e < NE){ s = geti(ei, e, f, NN); dd = geti(ei, (long long)NE + e, f, NN); }
  else { s = dd = e - NE; }
  u32 pos = atomicAdd(&cursor[dd], 1u);
  csr[pos] = (u32)s | ((u32)dd << 16);
}

// ---------- GEMM: 128x128 tile, BK=32 x 4, 8x8 quadrant microtile, reg-double-buffered ----------
// launch_bounds(256,3): VGPR cap ~170 so the 64-acc + 32-staging pipeline fits WITHOUT
// scratch spill (R16's (256,4) cap=128 spilled: WRITE_SIZE 20->52 MB). 3 blocks/CU.
__global__ __launch_bounds__(256, 3) void k_gemm(const void* __restrict__ Xv, const float* __restrict__ pr,
                                                 u16* __restrict__ xl, u16* __restrict__ xr,
                                                 const int* __restrict__ flags, int lay0)
{
  __shared__ float Xs[32][128];   // [k][row], row XOR-swizzled
  __shared__ float Ws[32][128];   // [k][col]
  int tid = threadIdx.x;
  int row0 = blockIdx.x * 128;
  int bc0  = blockIdx.y * 128;    // 0 -> xl, 128 -> xr
  int ty = tid >> 4, tx = tid & 15;
  int r = ty*4, c = tx*4;
  int isbf = lay0 ? flags[1] : 0;

  float4 bv0 = *(const float4*)(pr + 32768 + bc0 + c);
  float4 bv1 = *(const float4*)(pr + 32768 + bc0 + c + 64);
  float acc[2][2][4][4];
  #pragma unroll
  for (int qr = 0; qr < 2; ++qr)
    #pragma unroll
    for (int i = 0; i < 4; ++i){
      acc[qr][0][i][0] = bv0.x; acc[qr][0][i][1] = bv0.y;
      acc[qr][0][i][2] = bv0.z; acc[qr][0][i][3] = bv0.w;
      acc[qr][1][i][0] = bv1.x; acc[qr][1][i][1] = bv1.y;
      acc[qr][1][i][2] = bv1.z; acc[qr][1][i][3] = bv1.w;
    }

  // staging registers + fixed per-thread addressing
  float4 xv[4], wv[4];
  int xrow[4], xk4[4];
  #pragma unroll
  for (int i = 0; i < 4; ++i){
    int idx = tid + i*256;
    xrow[i] = idx >> 3;           // 0..127
    xk4[i]  = idx & 7;            // float4 slot in 32-k row
  }

  // prologue: load kt=0
  #pragma unroll
  for (int i = 0; i < 4; ++i)
    xv[i] = ld4(Xv, (size_t)(row0 + xrow[i])*D + 0 + xk4[i]*4, isbf);
  #pragma unroll
  for (int i = 0; i < 4; ++i){
    int idx = tid + i*256;
    int k = idx >> 5, c4 = idx & 31;
    wv[i] = *(const float4*)(pr + (size_t)k*256 + bc0 + c4*4);
  }

  #pragma unroll
  for (int kt = 0; kt < 4; ++kt){
    __syncthreads();               // previous compute done reading LDS
    #pragma unroll
    for (int i = 0; i < 4; ++i){
      int rs = xrow[i] ^ (xk4[i] << 2);
      Xs[xk4[i]*4+0][rs] = xv[i].x;
      Xs[xk4[i]*4+1][rs] = xv[i].y;
      Xs[xk4[i]*4+2][rs] = xv[i].z;
      Xs[xk4[i]*4+3][rs] = xv[i].w;
    }
    #pragma unroll
    for (int i = 0; i < 4; ++i){
      int idx = tid + i*256;
      int k = idx >> 5, c4 = idx & 31;
      *(float4*)&Ws[k][c4*4] = wv[i];
    }
    __syncthreads();
    if (kt < 3){                   // issue next tile's loads under compute
      #pragma unroll
      for (int i = 0; i < 4; ++i)
        xv[i] = ld4(Xv, (size_t)(row0 + xrow[i])*D + (kt+1)*32 + xk4[i]*4, isbf);
      #pragma unroll
      for (int i = 0; i < 4; ++i){
        int idx = tid + i*256;
        int k = idx >> 5, c4 = idx & 31;
        wv[i] = *(const float4*)(pr + (size_t)((kt+1)*32 + k)*256 + bc0 + c4*4);
      }
    }
    #pragma unroll 4
    for (int k = 0; k < 32; ++k){
      int swb = ((k >> 2) & 7) << 2;
      int ra = r ^ swb;
      float4 a0 = *(const float4*)&Xs[k][ra];
      float4 a1 = *(const float4*)&Xs[k][ra + 64];
      float4 w0 = *(const float4*)&Ws[k][c];
      float4 w1 = *(const float4*)&Ws[k][c + 64];
      #pragma unroll
      for (int qr = 0; qr < 2; ++qr){
        float ax = qr ? a1.x : a0.x, ay = qr ? a1.y : a0.y;
        float az = qr ? a1.z : a0.z, aw = qr ? a1.w : a0.w;
        #pragma unroll
        for (int qc = 0; qc < 2; ++qc){
          float wx = qc ? w1.x : w0.x, wy = qc ? w1.y : w0.y;
          float wz = qc ? w1.z : w0.z, ww = qc ? w1.w : w0.w;
          acc[qr][qc][0][0] = fmaf(ax, wx, acc[qr][qc][0][0]);
          acc[qr][qc][0][1] = fmaf(ax, wy, acc[qr][qc][0][1]);
          acc[qr][qc][0][2] = fmaf(ax, wz, acc[qr][qc][0][2]);
          acc[qr][qc][0][3] = fmaf(ax, ww, acc[qr][qc][0][3]);
          acc[qr][qc][1][0] = fmaf(ay, wx, acc[qr][qc][1][0]);
          acc[qr][qc][1][1] = fmaf(ay, wy, acc[qr][qc][1][1]);
          acc[qr][qc][1][2] = fmaf(ay, wz, acc[qr][qc][1][2]);
          acc[qr][qc][1][3] = fmaf(ay, ww, acc[qr][qc][1][3]);
          acc[qr][qc][2][0] = fmaf(az, wx, acc[qr][qc][2][0]);
          acc[qr][qc][2][1] = fmaf(az, wy, acc[qr][qc][2][1]);
          acc[qr][qc][2][2] = fmaf(az, wz, acc[qr][qc][2][2]);
          acc[qr][qc][2][3] = fmaf(az, ww, acc[qr][qc][2][3]);
          acc[qr][qc][3][0] = fmaf(aw, wx, acc[qr][qc][3][0]);
          acc[qr][qc][3][1] = fmaf(aw, wy, acc[qr][qc][3][1]);
          acc[qr][qc][3][2] = fmaf(aw, wz, acc[qr][qc][3][2]);
          acc[qr][qc][3][3] = fmaf(aw, ww, acc[qr][qc][3][3]);
        }
      }
    }
  }

  u16* base = bc0 ? xr : xl;
  #pragma unroll
  for (int qr = 0; qr < 2; ++qr)
    #pragma unroll
    for (int i = 0; i < 4; ++i){
      int grow = row0 + qr*64 + r + i;
      ushort4 o0 = make_ushort4(f2bf(acc[qr][0][i][0]), f2bf(acc[qr][0][i][1]),
                                f2bf(acc[qr][0][i][2]), f2bf(acc[qr][0][i][3]));
      ushort4 o1 = make_ushort4(f2bf(acc[qr][1][i][0]), f2bf(acc[qr][1][i][1]),
                                f2bf(acc[qr][1][i][2]), f2bf(acc[qr][1][i][3]));
      *(ushort4*)(base + (size_t)grow*D + c) = o0;
      *(ushort4*)(base + (size_t)grow*D + c + 64) = o1;
    }
}

// ---------- fused per-node attention: bf16 gather, depth-2 pipeline, defer-max ----------
__global__ __launch_bounds__(256) void k_node(const u16* __restrict__ xl, const u16* __restrict__ xr,
    const u32* __restrict__ offs, const u32* __restrict__ csr, const float* __restrict__ pr,
    float* __restrict__ hnew, void* __restrict__ out, const int* __restrict__ flags, int last)
{
  int node = blockIdx.x*4 + (threadIdx.x >> 6);
  int lane = threadIdx.x & 63;
  int half = lane >> 5;
  int c = (lane & 31) * 4;
  float4 xrv  = ldb4(xr + (size_t)node*D + c);
  float4 attv = *(const float4*)(pr + 33024 + c);
  u32 j0 = offs[node], j1 = offs[node + 1];

  float mx = -1e30f, ssum = 0.f;
  float4 acc = make_float4(0.f, 0.f, 0.f, 0.f);

  #define SRCJ(jj) ((int)(csr[(jj) < j1 ? (jj) : j0] & 0xFFFFu))
  u32 j = j0 + half;
  int s0 = SRCJ(j), s1 = SRCJ(j+2);
  float4 g0 = ldb4(xl + (size_t)s0*D + c);
  float4 g1 = ldb4(xl + (size_t)s1*D + c);
  int s2 = SRCJ(j+4), s3 = SRCJ(j+6);

  for (; j < j1; j += 4){
    float4 n0 = ldb4(xl + (size_t)s2*D + c);
    float4 n1 = ldb4(xl + (size_t)s3*D + c);
    int t0 = SRCJ(j+8), t1 = SRCJ(j+10);

    {
      float m, p;
      m = g0.x + xrv.x; p = fmaxf(m, 0.2f*m) * attv.x;
      m = g0.y + xrv.y; p = fmaf(fmaxf(m, 0.2f*m), attv.y, p);
      m = g0.z + xrv.z; p = fmaf(fmaxf(m, 0.2f*m), attv.z, p);
      m = g0.w + xrv.w; p = fmaf(fmaxf(m, 0.2f*m), attv.w, p);
      p += __shfl_xor(p, 1, 64);
      p += __shfl_xor(p, 2, 64);
      p += __shfl_xor(p, 4, 64);
      if (p > mx + 8.f){
        float eo = __expf(mx - p);
        ssum  *= eo;
        acc.x *= eo; acc.y *= eo; acc.z *= eo; acc.w *= eo;
        mx = p;
      }
      float en = __expf(p - mx);
      ssum += en;
      acc.x = fmaf(en, g0.x, acc.x);
      acc.y = fmaf(en, g0.y, acc.y);
      acc.z = fmaf(en, g0.z, acc.z);
      acc.w = fmaf(en, g0.w, acc.w);
    }
    if (j + 2 < j1){
      float m, p;
      m = g1.x + xrv.x; p = fmaxf(m, 0.2f*m) * attv.x;
      m = g1.y + xrv.y; p = fmaf(fmaxf(m, 0.2f*m), attv.y, p);
      m = g1.z + xrv.z; p = fmaf(fmaxf(m, 0.2f*m), attv.z, p);
      m = g1.w + xrv.w; p = fmaf(fmaxf(m, 0.2f*m), attv.w, p);
      p += __shfl_xor(p, 1, 64);
      p += __shfl_xor(p, 2, 64);
      p += __shfl_xor(p, 4, 64);
      if (p > mx + 8.f){
        float eo = __expf(mx - p);
        ssum  *= eo;
        acc.x *= eo; acc.y *= eo; acc.z *= eo; acc.w *= eo;
        mx = p;
      }
      float en = __expf(p - mx);
      ssum += en;
      acc.x = fmaf(en, g1.x, acc.x);
      acc.y = fmaf(en, g1.y, acc.y);
      acc.z = fmaf(en, g1.z, acc.z);
      acc.w = fmaf(en, g1.w, acc.w);
    }
    g0 = n0; g1 = n1; s2 = t0; s3 = t1;
  }
  #undef SRCJ

  float mo = __shfl_xor(mx, 32, 64);
  float so = __shfl_xor(ssum, 32, 64);
  float ax = __shfl_xor(acc.x, 32, 64);
  float ay = __shfl_xor(acc.y, 32, 64);
  float az = __shfl_xor(acc.z, 32, 64);
  float aw = __shfl_xor(acc.w, 32, 64);
  float n  = fmaxf(mx, mo);
  float e0 = __expf(mx - n), e1 = __expf(mo - n);
  ssum  = ssum*e0 + so*e1;
  acc.x = acc.x*e0 + ax*e1;
  acc.y = acc.y*e0 + ay*e1;
  acc.z = acc.z*e0 + az*e1;
  acc.w = acc.w*e0 + aw*e1;

  if (half == 0){
    float inv = 1.0f / fmaxf(ssum, 1e-30f);
    float4 bv = *(const float4*)(pr + 33152 + c);
    float4 v = make_float4(acc.x*inv + bv.x, acc.y*inv + bv.y,
                           acc.z*inv + bv.z, acc.w*inv + bv.w);
    if (!last){
      v.x = fmaxf(v.x, 0.f); v.y = fmaxf(v.y, 0.f);
      v.z = fmaxf(v.z, 0.f); v.w = fmaxf(v.w, 0.f);
      *(float4*)(hnew + (size_t)node*D + c) = v;
    } else {
      *(float4*)(hnew + (size_t)node*D + c) = v;
      int isbf = flags[1];
      long long o = (long long)NG*D + (long long)node*D + c;
      stf(out, o+0, v.x, isbf); stf(out, o+1, v.y, isbf);
      stf(out, o+2, v.z, isbf); stf(out, o+3, v.w, isbf);
    }
  }
}

// ---------- two-stage mean pool ----------
__global__ __launch_bounds__(256) void k_pool1(const float* __restrict__ h, const u32* __restrict__ bnd,
                                               float* __restrict__ pool){
  int g = blockIdx.x >> 6, sl = blockIdx.x & 63;
  int ch = threadIdx.x & 127, ro = threadIdx.x >> 7;
  u32 b0 = bnd[g], b1 = bnd[g + 1];
  float acc = 0.f;
  for (u32 r = b0 + sl*2 + ro; r < b1; r += 128) acc += h[(size_t)r*D + ch];
  unsafeAtomicAdd(&pool[g*D + ch], acc);
}

__global__ void k_pool2(const float* __restrict__ pool, const u32* __restrict__ bnd,
                        void* __restrict__ out, const int* __restrict__ flags){
  int i = blockIdx.x*256 + threadIdx.x;
  if (i >= NG*D) return;
  int g = i >> 7;
  float c = (float)(bnd[g + 1] - bnd[g]);
  stf(out, i, pool[i] / fmaxf(c, 1.f), flags[1]);
}

extern "C" void kernel_launch(void* const* d_in, const int* in_sizes, int n_in,
                              void* d_out, int out_size, void* d_ws, size_t ws_size,
                              hipStream_t stream) {
  const void* x     = d_in[0];
  const void* ei    = d_in[1];
  const void* batch = d_in[2];

  const long long nf = (long long)NN*D*3 + 3*PL + NG*D;
  const long long nu = (NN + 1) + NN + ET + (NG + 1) + 2 + 160;
  if (ws_size < (size_t)(nf + nu)*4 + 256) return;

  float* ws    = (float*)d_ws;
  float* xf    = ws;                               // NN*D f32 (h buffer each layer)
  u16*  xl    = (u16*)(xf + (size_t)NN*D);         // NN*D bf16
  u16*  xr    = (u16*)(xf + (size_t)NN*D*2);       // NN*D bf16
  float* prm   = xf + (size_t)NN*D*3;              // 3*PL
  float* pool  = prm + 3*PL;                       // NG*D
  u32*  offs   = (u32*)(pool + NG*D);              // NN+1
  u32*  cursor = offs + (NN + 1);                  // NN
  u32*  csr    = cursor + NN;                      // ET
  u32*  bnd    = csr + ET;                         // NG+1
  u32*  psum   = bnd + (NG + 1);                   // 160
  int*  flags  = (int*)(psum + 160);               // 2

  k_setup<<<169, 256, 0, stream>>>(ei, x, flags, cursor, pool);
  P18 ps;
  for (int i = 0; i < 18; ++i) ps.p[i] = d_in[3 + i];
  k_prep<<<390, 256, 0, stream>>>(ps, prm, flags);

  k_hist<<<ET/256, 256, 0, stream>>>(ei, cursor, flags);
  k_scanA<<<160, 256, 0, stream>>>(cursor, psum);
  k_scanB<<<1, 256, 0, stream>>>(psum, offs, batch, bnd, flags);
  k_scanC<<<160, 256, 0, stream>>>(cursor, offs, psum);
  k_scatter<<<ET/256, 256, 0, stream>>>(ei, cursor, csr, flags);

  for (int l = 0; l < 3; ++l){
    const float* p = prm + (size_t)l*PL;
    const void* Xin = (l == 0) ? x : (const void*)xf;
    k_gemm<<<dim3(NN/128, 2), 256, 0, stream>>>(Xin, p, xl, xr, flags, l == 0);
    k_node<<<NN/4, 256, 0, stream>>>(xl, xr, offs, csr, p, xf, d_out, flags, l == 2);
  }
  k_pool1<<<NG*64, 256, 0, stream>>>(xf, bnd, pool);
  k_pool2<<<8, 256, 0, stream>>>(pool, bnd, d_out, flags);
}

// Round 18
// 338.035 us; speedup vs baseline: 1.0631x; 1.0450x over previous
//
#include <hip/hip_runtime.h>

#define NN 40960
#define NE 655360
#define ET (NE + NN)        // 696320 edges incl self-loops
#define D 128
#define NG 16
#define PL 33280            // params per layer: WF[32768], bf[256], att[128], b[128]

typedef unsigned int u32;
typedef unsigned short u16;
typedef long long i64;

struct P18 { const void* p[18]; };

__device__ __forceinline__ float bf2f(u16 v){ return __uint_as_float(((u32)v)<<16); }
__device__ __forceinline__ u16 f2bf(float f){
  u32 u = __float_as_uint(f);
  return (u16)((u + 0x7FFFu + ((u>>16)&1u)) >> 16);
}
__device__ __forceinline__ int geti(const void* p, long long i, int f64, int bound){
  long long v = f64 ? ((const i64*)p)[i] : (long long)((const int*)p)[i];
  int x = (int)v;
  return (x < 0) ? 0 : ((x >= bound) ? bound-1 : x);
}
__device__ __forceinline__ void stf(void* p, long long i, float v, int isbf){
  if (isbf) ((u16*)p)[i] = f2bf(v); else ((float*)p)[i] = v;
}
__device__ __forceinline__ float rdf(const void* p, int i, int isbf){
  return isbf ? bf2f(((const u16*)p)[i]) : ((const float*)p)[i];
}
__device__ __forceinline__ float4 ld4(const void* p, size_t foff, int isbf){
  if (!isbf) return *(const float4*)((const float*)p + foff);
  ushort4 u = *(const ushort4*)((const u16*)p + foff);
  return make_float4(bf2f(u.x), bf2f(u.y), bf2f(u.z), bf2f(u.w));
}
__device__ __forceinline__ float4 ldb4(const u16* p){
  ushort4 u = *(const ushort4*)p;
  return make_float4(bf2f(u.x), bf2f(u.y), bf2f(u.z), bf2f(u.w));
}

// block 0: dtype detect; blocks 1..160: zero cursor; blocks 161..168: zero pool
__global__ void k_setup(const void* __restrict__ ei, const void* __restrict__ x,
                        int* __restrict__ flags, u32* __restrict__ cursor, float* __restrict__ pool){
  int b = blockIdx.x;
  if (b == 0){
    __shared__ int nz, cnt;
    if (threadIdx.x == 0){ nz = 0; cnt = 0; }
    __syncthreads();
    if (((const int*)ei)[2*threadIdx.x + 1] != 0) atomicAdd(&nz, 1);
    if (threadIdx.x < 128){
      u16 v = ((const u16*)x)[2*threadIdx.x];
      int ex = (v >> 7) & 0xFF;
      if (ex >= 100 && ex <= 140) atomicAdd(&cnt, 1);
    }
    __syncthreads();
    if (threadIdx.x == 0){
      flags[0] = (nz == 0) ? 1 : 0;
      flags[1] = (cnt >= 64) ? 1 : 0;
    }
  } else if (b <= 160){
    cursor[(b-1)*256 + threadIdx.x] = 0u;
  } else {
    int i = (b-161)*256 + threadIdx.x;
    if (i < NG*D) pool[i] = 0.f;
  }
}

// param pack only (130 blocks/layer)
__global__ void k_prep(P18 ps, float* __restrict__ prm, const int* __restrict__ flags){
  int b = blockIdx.x;
  int l = b / 130;
  int i = (b % 130)*256 + threadIdx.x;
  const void* Wl  = ps.p[6*l+0];
  const void* bl  = ps.p[6*l+1];
  const void* Wr  = ps.p[6*l+2];
  const void* br  = ps.p[6*l+3];
  const void* att = ps.p[6*l+4];
  const void* bb  = ps.p[6*l+5];
  int isbf = flags[1];
  float v;
  if (i < 32768){
    int k = i >> 8, gc = i & 255;
    v = (gc < 128) ? rdf(Wl, k*128 + gc, isbf) : rdf(Wr, k*128 + gc - 128, isbf);
  }
  else if (i < 33024){ int gc = i - 32768; v = (gc < 128) ? rdf(bl, gc, isbf) : rdf(br, gc - 128, isbf); }
  else if (i < 33152) v = rdf(att, i - 33024, isbf);
  else                v = rdf(bb, i - 33152, isbf);
  prm[(size_t)l*PL + i] = v;
}

// ---------- CSR build (by dst, self-loops appended); entry packs src|dst<<16 ----------
__global__ void k_hist(const void* __restrict__ ei, u32* __restrict__ cursor, const int* __restrict__ flags){
  int e = blockIdx.x*256 + threadIdx.x;
  if (e >= ET) return;
  int dd = (e < NE) ? geti(ei, (long long)NE + e, flags[0], NN) : e - NE;
  atomicAdd(&cursor[dd], 1u);
}

__global__ __launch_bounds__(256) void k_scanA(const u32* __restrict__ cursor, u32* __restrict__ psum){
  __shared__ u32 red[256];
  int t = threadIdx.x;
  red[t] = cursor[blockIdx.x*256 + t];
  __syncthreads();
  #pragma unroll
  for (int off = 128; off > 0; off >>= 1){
    if (t < off) red[t] += red[t + off];
    __syncthreads();
  }
  if (t == 0) psum[blockIdx.x] = red[0];
}

__global__ __launch_bounds__(256) void k_scanB(u32* __restrict__ psum, u32* __restrict__ offs,
                                               const void* __restrict__ batch, u32* __restrict__ bnd,
                                               const int* __restrict__ flags){
  __shared__ u32 sh[256];
  int t = threadIdx.x;
  sh[t] = (t < 160) ? psum[t] : 0u;
  __syncthreads();
  #pragma unroll
  for (int off = 1; off < 256; off <<= 1){
    u32 add = (t >= off) ? sh[t - off] : 0u;
    __syncthreads();
    sh[t] += add;
    __syncthreads();
  }
  if (t < 160) psum[t] = (t == 0) ? 0u : sh[t - 1];
  if (t == 160) offs[NN] = sh[159];
  if (t >= 192 && t <= 192 + NG){
    int g = t - 192;
    if (g == NG){ bnd[NG] = NN; }
    else {
      int f = flags[0];
      int lo = 0, hi = NN;
      while (lo < hi){
        int mid = (lo + hi) >> 1;
        if (geti(batch, mid, f, NG) < g) lo = mid + 1; else hi = mid;
      }
      bnd[g] = (u32)lo;
    }
  }
}

__global__ __launch_bounds__(256) void k_scanC(u32* __restrict__ cursor, u32* __restrict__ offs,
                                               const u32* __restrict__ psum){
  __shared__ u32 sh[256];
  int t = threadIdx.x;
  int gi = blockIdx.x*256 + t;
  u32 v = cursor[gi];
  sh[t] = v;
  __syncthreads();
  #pragma unroll
  for (int off = 1; off < 256; off <<= 1){
    u32 add = (t >= off) ? sh[t - off] : 0u;
    __syncthreads();
    sh[t] += add;
    __syncthreads();
  }
  u32 excl = ((t > 0) ? sh[t - 1] : 0u) + psum[blockIdx.x];
  offs[gi] = excl;
  cursor[gi] = excl;
}

__global__ void k_scatter(const void* __restrict__ ei, u32* __restrict__ cursor,
                          u32* __restrict__ csr, const int* __restrict__ flags){
  int e = blockIdx.x*256 + threadIdx.x;
  if (e >= ET) return;
  int f = flags[0];
  int s, dd;
  if (e < NE){ s = geti(ei, e, f, NN); dd = geti(ei, (long long)NE + e, f, NN); }
  else { s = dd = e - NE; }
  u32 pos = atomicAdd(&cursor[dd], 1u);
  csr[pos] = (u32)s | ((u32)dd << 16);
}

// ---------- GEMM: 128x128 tile, BK=32 x 4, 8x8 quadrant microtile ----------
// Reg-double-buffered staging via NAMED float4 scalars (no arrays -> no scratch
// heuristic; R16/R17's xv[]/wv[] arrays were placed in scratch: 21-32 MB WRITE).
__global__ __launch_bounds__(256, 3) void k_gemm(const void* __restrict__ Xv, const float* __restrict__ pr,
                                                 u16* __restrict__ xl, u16* __restrict__ xr,
                                                 const int* __restrict__ flags, int lay0)
{
  __shared__ float Xs[32][128];   // [k][row], row XOR-swizzled
  __shared__ float Ws[32][128];   // [k][col]
  int tid = threadIdx.x;
  int row0 = blockIdx.x * 128;
  int bc0  = blockIdx.y * 128;    // 0 -> xl, 128 -> xr
  int ty = tid >> 4, tx = tid & 15;
  int r = ty*4, c = tx*4;
  int isbf = lay0 ? flags[1] : 0;

  // fixed per-thread addressing
  int xrw = tid >> 3;             // 0..31 ; rows xrw, xrw+32, xrw+64, xrw+96
  int xk4 = tid & 7;              // float4 slot in 32-k row
  int wk  = tid >> 5;             // 0..7  ; ks wk, wk+8, wk+16, wk+24
  int wc4 = tid & 31;

  float4 bv0 = *(const float4*)(pr + 32768 + bc0 + c);
  float4 bv1 = *(const float4*)(pr + 32768 + bc0 + c + 64);
  float acc[2][2][4][4];
  #pragma unroll
  for (int qr = 0; qr < 2; ++qr)
    #pragma unroll
    for (int i = 0; i < 4; ++i){
      acc[qr][0][i][0] = bv0.x; acc[qr][0][i][1] = bv0.y;
      acc[qr][0][i][2] = bv0.z; acc[qr][0][i][3] = bv0.w;
      acc[qr][1][i][0] = bv1.x; acc[qr][1][i][1] = bv1.y;
      acc[qr][1][i][2] = bv1.z; acc[qr][1][i][3] = bv1.w;
    }

  // prologue: load kt=0 into named staging regs
  float4 xv0 = ld4(Xv, (size_t)(row0 + xrw     )*D + xk4*4, isbf);
  float4 xv1 = ld4(Xv, (size_t)(row0 + xrw + 32)*D + xk4*4, isbf);
  float4 xv2 = ld4(Xv, (size_t)(row0 + xrw + 64)*D + xk4*4, isbf);
  float4 xv3 = ld4(Xv, (size_t)(row0 + xrw + 96)*D + xk4*4, isbf);
  float4 wv0 = *(const float4*)(pr + (size_t)(wk     )*256 + bc0 + wc4*4);
  float4 wv1 = *(const float4*)(pr + (size_t)(wk +  8)*256 + bc0 + wc4*4);
  float4 wv2 = *(const float4*)(pr + (size_t)(wk + 16)*256 + bc0 + wc4*4);
  float4 wv3 = *(const float4*)(pr + (size_t)(wk + 24)*256 + bc0 + wc4*4);

  #pragma unroll
  for (int kt = 0; kt < 4; ++kt){
    __syncthreads();               // previous compute done reading LDS
    {
      int rs0 = (xrw     ) ^ (xk4 << 2);
      int rs1 = (xrw + 32) ^ (xk4 << 2);
      int rs2 = (xrw + 64) ^ (xk4 << 2);
      int rs3 = (xrw + 96) ^ (xk4 << 2);
      Xs[xk4*4+0][rs0] = xv0.x; Xs[xk4*4+1][rs0] = xv0.y;
      Xs[xk4*4+2][rs0] = xv0.z; Xs[xk4*4+3][rs0] = xv0.w;
      Xs[xk4*4+0][rs1] = xv1.x; Xs[xk4*4+1][rs1] = xv1.y;
      Xs[xk4*4+2][rs1] = xv1.z; Xs[xk4*4+3][rs1] = xv1.w;
      Xs[xk4*4+0][rs2] = xv2.x; Xs[xk4*4+1][rs2] = xv2.y;
      Xs[xk4*4+2][rs2] = xv2.z; Xs[xk4*4+3][rs2] = xv2.w;
      Xs[xk4*4+0][rs3] = xv3.x; Xs[xk4*4+1][rs3] = xv3.y;
      Xs[xk4*4+2][rs3] = xv3.z; Xs[xk4*4+3][rs3] = xv3.w;
      *(float4*)&Ws[wk     ][wc4*4] = wv0;
      *(float4*)&Ws[wk +  8][wc4*4] = wv1;
      *(float4*)&Ws[wk + 16][wc4*4] = wv2;
      *(float4*)&Ws[wk + 24][wc4*4] = wv3;
    }
    __syncthreads();
    if (kt < 3){                   // issue next tile's loads under compute
      int kb = (kt+1)*32;
      xv0 = ld4(Xv, (size_t)(row0 + xrw     )*D + kb + xk4*4, isbf);
      xv1 = ld4(Xv, (size_t)(row0 + xrw + 32)*D + kb + xk4*4, isbf);
      xv2 = ld4(Xv, (size_t)(row0 + xrw + 64)*D + kb + xk4*4, isbf);
      xv3 = ld4(Xv, (size_t)(row0 + xrw + 96)*D + kb + xk4*4, isbf);
      wv0 = *(const float4*)(pr + (size_t)(kb + wk     )*256 + bc0 + wc4*4);
      wv1 = *(const float4*)(pr + (size_t)(kb + wk +  8)*256 + bc0 + wc4*4);
      wv2 = *(const float4*)(pr + (size_t)(kb + wk + 16)*256 + bc0 + wc4*4);
      wv3 = *(const float4*)(pr + (size_t)(kb + wk + 24)*256 + bc0 + wc4*4);
    }
    #pragma unroll 4
    for (int k = 0; k < 32; ++k){
      int swb = ((k >> 2) & 7) << 2;
      int ra = r ^ swb;
      float4 a0 = *(const float4*)&Xs[k][ra];
      float4 a1 = *(const float4*)&Xs[k][ra + 64];
      float4 w0 = *(const float4*)&Ws[k][c];
      float4 w1 = *(const float4*)&Ws[k][c + 64];
      #pragma unroll
      for (int qr = 0; qr < 2; ++qr){
        float ax = qr ? a1.x : a0.x, ay = qr ? a1.y : a0.y;
        float az = qr ? a1.z : a0.z, aw = qr ? a1.w : a0.w;
        #pragma unroll
        for (int qc = 0; qc < 2; ++qc){
          float wx = qc ? w1.x : w0.x, wy = qc ? w1.y : w0.y;
          float wz = qc ? w1.z : w0.z, ww = qc ? w1.w : w0.w;
          acc[qr][qc][0][0] = fmaf(ax, wx, acc[qr][qc][0][0]);
          acc[qr][qc][0][1] = fmaf(ax, wy, acc[qr][qc][0][1]);
          acc[qr][qc][0][2] = fmaf(ax, wz, acc[qr][qc][0][2]);
          acc[qr][qc][0][3] = fmaf(ax, ww, acc[qr][qc][0][3]);
          acc[qr][qc][1][0] = fmaf(ay, wx, acc[qr][qc][1][0]);
          acc[qr][qc][1][1] = fmaf(ay, wy, acc[qr][qc][1][1]);
          acc[qr][qc][1][2] = fmaf(ay, wz, acc[qr][qc][1][2]);
          acc[qr][qc][1][3] = fmaf(ay, ww, acc[qr][qc][1][3]);
          acc[qr][qc][2][0] = fmaf(az, wx, acc[qr][qc][2][0]);
          acc[qr][qc][2][1] = fmaf(az, wy, acc[qr][qc][2][1]);
          acc[qr][qc][2][2] = fmaf(az, wz, acc[qr][qc][2][2]);
          acc[qr][qc][2][3] = fmaf(az, ww, acc[qr][qc][2][3]);
          acc[qr][qc][3][0] = fmaf(aw, wx, acc[qr][qc][3][0]);
          acc[qr][qc][3][1] = fmaf(aw, wy, acc[qr][qc][3][1]);
          acc[qr][qc][3][2] = fmaf(aw, wz, acc[qr][qc][3][2]);
          acc[qr][qc][3][3] = fmaf(aw, ww, acc[qr][qc][3][3]);
        }
      }
    }
  }

  u16* base = bc0 ? xr : xl;
  #pragma unroll
  for (int qr = 0; qr < 2; ++qr)
    #pragma unroll
    for (int i = 0; i < 4; ++i){
      int grow = row0 + qr*64 + r + i;
      ushort4 o0 = make_ushort4(f2bf(acc[qr][0][i][0]), f2bf(acc[qr][0][i][1]),
                                f2bf(acc[qr][0][i][2]), f2bf(acc[qr][0][i][3]));
      ushort4 o1 = make_ushort4(f2bf(acc[qr][1][i][0]), f2bf(acc[qr][1][i][1]),
                                f2bf(acc[qr][1][i][2]), f2bf(acc[qr][1][i][3]));
      *(ushort4*)(base + (size_t)grow*D + c) = o0;
      *(ushort4*)(base + (size_t)grow*D + c + 64) = o1;
    }
}

// ---------- fused per-node attention: bf16 gather, depth-2 pipeline, defer-max ----------
__global__ __launch_bounds__(256) void k_node(const u16* __restrict__ xl, const u16* __restrict__ xr,
    const u32* __restrict__ offs, const u32* __restrict__ csr, const float* __restrict__ pr,
    float* __restrict__ hnew, void* __restrict__ out, const int* __restrict__ flags, int last)
{
  int node = blockIdx.x*4 + (threadIdx.x >> 6);
  int lane = threadIdx.x & 63;
  int half = lane >> 5;
  int c = (lane & 31) * 4;
  float4 xrv  = ldb4(xr + (size_t)node*D + c);
  float4 attv = *(const float4*)(pr + 33024 + c);
  u32 j0 = offs[node], j1 = offs[node + 1];

  float mx = -1e30f, ssum = 0.f;
  float4 acc = make_float4(0.f, 0.f, 0.f, 0.f);

  #define SRCJ(jj) ((int)(csr[(jj) < j1 ? (jj) : j0] & 0xFFFFu))
  u32 j = j0 + half;
  int s0 = SRCJ(j), s1 = SRCJ(j+2);
  float4 g0 = ldb4(xl + (size_t)s0*D + c);
  float4 g1 = ldb4(xl + (size_t)s1*D + c);
  int s2 = SRCJ(j+4), s3 = SRCJ(j+6);

  for (; j < j1; j += 4){
    float4 n0 = ldb4(xl + (size_t)s2*D + c);
    float4 n1 = ldb4(xl + (size_t)s3*D + c);
    int t0 = SRCJ(j+8), t1 = SRCJ(j+10);

    {
      float m, p;
      m = g0.x + xrv.x; p = fmaxf(m, 0.2f*m) * attv.x;
      m = g0.y + xrv.y; p = fmaf(fmaxf(m, 0.2f*m), attv.y, p);
      m = g0.z + xrv.z; p = fmaf(fmaxf(m, 0.2f*m), attv.z, p);
      m = g0.w + xrv.w; p = fmaf(fmaxf(m, 0.2f*m), attv.w, p);
      p += __shfl_xor(p, 1, 64);
      p += __shfl_xor(p, 2, 64);
      p += __shfl_xor(p, 4, 64);
      if (p > mx + 8.f){
        float eo = __expf(mx - p);
        ssum  *= eo;
        acc.x *= eo; acc.y *= eo; acc.z *= eo; acc.w *= eo;
        mx = p;
      }
      float en = __expf(p - mx);
      ssum += en;
      acc.x = fmaf(en, g0.x, acc.x);
      acc.y = fmaf(en, g0.y, acc.y);
      acc.z = fmaf(en, g0.z, acc.z);
      acc.w = fmaf(en, g0.w, acc.w);
    }
    if (j + 2 < j1){
      float m, p;
      m = g1.x + xrv.x; p = fmaxf(m, 0.2f*m) * attv.x;
      m = g1.y + xrv.y; p = fmaf(fmaxf(m, 0.2f*m), attv.y, p);
      m = g1.z + xrv.z; p = fmaf(fmaxf(m, 0.2f*m), attv.z, p);
      m = g1.w + xrv.w; p = fmaf(fmaxf(m, 0.2f*m), attv.w, p);
      p += __shfl_xor(p, 1, 64);
      p += __shfl_xor(p, 2, 64);
      p += __shfl_xor(p, 4, 64);
      if (p > mx + 8.f){
        float eo = __expf(mx - p);
        ssum  *= eo;
        acc.x *= eo; acc.y *= eo; acc.z *= eo; acc.w *= eo;
        mx = p;
      }
      float en = __expf(p - mx);
      ssum += en;
      acc.x = fmaf(en, g1.x, acc.x);
      acc.y = fmaf(en, g1.y, acc.y);
      acc.z = fmaf(en, g1.z, acc.z);
      acc.w = fmaf(en, g1.w, acc.w);
    }
    g0 = n0; g1 = n1; s2 = t0; s3 = t1;
  }
  #undef SRCJ

  float mo = __shfl_xor(mx, 32, 64);
  float so = __shfl_xor(ssum, 32, 64);
  float ax = __shfl_xor(acc.x, 32, 64);
  float ay = __shfl_xor(acc.y, 32, 64);
  float az = __shfl_xor(acc.z, 32, 64);
  float aw = __shfl_xor(acc.w, 32, 64);
  float n  = fmaxf(mx, mo);
  float e0 = __expf(mx - n), e1 = __expf(mo - n);
  ssum  = ssum*e0 + so*e1;
  acc.x = acc.x*e0 + ax*e1;
  acc.y = acc.y*e0 + ay*e1;
  acc.z = acc.z*e0 + az*e1;
  acc.w = acc.w*e0 + aw*e1;

  if (half == 0){
    float inv = 1.0f / fmaxf(ssum, 1e-30f);
    float4 bv = *(const float4*)(pr + 33152 + c);
    float4 v = make_float4(acc.x*inv + bv.x, acc.y*inv + bv.y,
                           acc.z*inv + bv.z, acc.w*inv + bv.w);
    if (!last){
      v.x = fmaxf(v.x, 0.f); v.y = fmaxf(v.y, 0.f);
      v.z = fmaxf(v.z, 0.f); v.w = fmaxf(v.w, 0.f);
      *(float4*)(hnew + (size_t)node*D + c) = v;
    } else {
      *(float4*)(hnew + (size_t)node*D + c) = v;
      int isbf = flags[1];
      long long o = (long long)NG*D + (long long)node*D + c;
      stf(out, o+0, v.x, isbf); stf(out, o+1, v.y, isbf);
      stf(out, o+2, v.z, isbf); stf(out, o+3, v.w, isbf);
    }
  }
}

// ---------- two-stage mean pool ----------
__global__ __launch_bounds__(256) void k_pool1(const float* __restrict__ h, const u32* __restrict__ bnd,
                                               float* __restrict__ pool){
  int g = blockIdx.x >> 6, sl = blockIdx.x & 63;
  int ch = threadIdx.x & 127, ro = threadIdx.x >> 7;
  u32 b0 = bnd[g], b1 = bnd[g + 1];
  float acc = 0.f;
  for (u32 r = b0 + sl*2 + ro; r < b1; r += 128) acc += h[(size_t)r*D + ch];
  unsafeAtomicAdd(&pool[g*D + ch], acc);
}

__global__ void k_pool2(const float* __restrict__ pool, const u32* __restrict__ bnd,
                        void* __restrict__ out, const int* __restrict__ flags){
  int i = blockIdx.x*256 + threadIdx.x;
  if (i >= NG*D) return;
  int g = i >> 7;
  float c = (float)(bnd[g + 1] - bnd[g]);
  stf(out, i, pool[i] / fmaxf(c, 1.f), flags[1]);
}

extern "C" void kernel_launch(void* const* d_in, const int* in_sizes, int n_in,
                              void* d_out, int out_size, void* d_ws, size_t ws_size,
                              hipStream_t stream) {
  const void* x     = d_in[0];
  const void* ei    = d_in[1];
  const void* batch = d_in[2];

  const long long nf = (long long)NN*D*3 + 3*PL + NG*D;
  const long long nu = (NN + 1) + NN + ET + (NG + 1) + 2 + 160;
  if (ws_size < (size_t)(nf + nu)*4 + 256) return;

  float* ws    = (float*)d_ws;
  float* xf    = ws;                               // NN*D f32 (h buffer each layer)
  u16*  xl    = (u16*)(xf + (size_t)NN*D);         // NN*D bf16
  u16*  xr    = (u16*)(xf + (size_t)NN*D*2);       // NN*D bf16
  float* prm   = xf + (size_t)NN*D*3;              // 3*PL
  float* pool  = prm + 3*PL;                       // NG*D
  u32*  offs   = (u32*)(pool + NG*D);              // NN+1
  u32*  cursor = offs + (NN + 1);                  // NN
  u32*  csr    = cursor + NN;                      // ET
  u32*  bnd    = csr + ET;                         // NG+1
  u32*  psum   = bnd + (NG + 1);                   // 160
  int*  flags  = (int*)(psum + 160);               // 2

  k_setup<<<169, 256, 0, stream>>>(ei, x, flags, cursor, pool);
  P18 ps;
  for (int i = 0; i < 18; ++i) ps.p[i] = d_in[3 + i];
  k_prep<<<390, 256, 0, stream>>>(ps, prm, flags);

  k_hist<<<ET/256, 256, 0, stream>>>(ei, cursor, flags);
  k_scanA<<<160, 256, 0, stream>>>(cursor, psum);
  k_scanB<<<1, 256, 0, stream>>>(psum, offs, batch, bnd, flags);
  k_scanC<<<160, 256, 0, stream>>>(cursor, offs, psum);
  k_scatter<<<ET/256, 256, 0, stream>>>(ei, cursor, csr, flags);

  for (int l = 0; l < 3; ++l){
    const float* p = prm + (size_t)l*PL;
    const void* Xin = (l == 0) ? x : (const void*)xf;
    k_gemm<<<dim3(NN/128, 2), 256, 0, stream>>>(Xin, p, xl, xr, flags, l == 0);
    k_node<<<NN/4, 256, 0, stream>>>(xl, xr, offs, csr, p, xf, d_out, flags, l == 2);
  }
  k_pool1<<<NG*64, 256, 0, stream>>>(xf, bnd, pool);
  k_pool2<<<8, 256, 0, stream>>>(pool, bnd, d_out, flags);
}

// Round 20
// 307.441 us; speedup vs baseline: 1.1689x; 1.0995x over previous
//
#include <hip/hip_runtime.h>

#define NN 40960
#define NE 655360
#define ET (NE + NN)        // 696320 edges incl self-loops
#define D 128
#define NG 16
#define PL 16896            // floats/layer: WT bf16[256*128] = 16384 floats, bf[256], att[128], b[128]

typedef unsigned int u32;
typedef unsigned short u16;
typedef long long i64;
typedef __attribute__((ext_vector_type(8))) short bf8v;   // 8 bf16 (4 VGPRs)
typedef __attribute__((ext_vector_type(4))) float f4v;    // 4 fp32 acc

struct P18 { const void* p[18]; };

__device__ __forceinline__ float bf2f(u16 v){ return __uint_as_float(((u32)v)<<16); }
__device__ __forceinline__ u16 f2bf(float f){
  u32 u = __float_as_uint(f);
  return (u16)((u + 0x7FFFu + ((u>>16)&1u)) >> 16);
}
__device__ __forceinline__ int geti(const void* p, long long i, int f64, int bound){
  long long v = f64 ? ((const i64*)p)[i] : (long long)((const int*)p)[i];
  int x = (int)v;
  return (x < 0) ? 0 : ((x >= bound) ? bound-1 : x);
}
__device__ __forceinline__ void stf(void* p, long long i, float v, int isbf){
  if (isbf) ((u16*)p)[i] = f2bf(v); else ((float*)p)[i] = v;
}
__device__ __forceinline__ float rdf(const void* p, long long i, int isbf){
  return isbf ? bf2f(((const u16*)p)[i]) : ((const float*)p)[i];
}
__device__ __forceinline__ float4 ldb4(const u16* p){
  ushort4 u = *(const ushort4*)p;
  return make_float4(bf2f(u.x), bf2f(u.y), bf2f(u.z), bf2f(u.w));
}

// block 0: dtype detect; blocks 1..160: zero cursor; blocks 161..168: zero pool
__global__ void k_setup(const void* __restrict__ ei, const void* __restrict__ x,
                        int* __restrict__ flags, u32* __restrict__ cursor, float* __restrict__ pool){
  int b = blockIdx.x;
  if (b == 0){
    __shared__ int nz, cnt;
    if (threadIdx.x == 0){ nz = 0; cnt = 0; }
    __syncthreads();
    if (((const int*)ei)[2*threadIdx.x + 1] != 0) atomicAdd(&nz, 1);
    if (threadIdx.x < 128){
      u16 v = ((const u16*)x)[2*threadIdx.x];
      int ex = (v >> 7) & 0xFF;
      if (ex >= 100 && ex <= 140) atomicAdd(&cnt, 1);
    }
    __syncthreads();
    if (threadIdx.x == 0){
      flags[0] = (nz == 0) ? 1 : 0;
      flags[1] = (cnt >= 64) ? 1 : 0;
    }
  } else if (b <= 160){
    cursor[(b-1)*256 + threadIdx.x] = 0u;
  } else {
    int i = (b-161)*256 + threadIdx.x;
    if (i < NG*D) pool[i] = 0.f;
  }
}

// blocks [0,390): param pack (130/layer over 33280 logical entries): WT bf16 transposed + f32 biases
// blocks [390, 390+20480): x -> xb bf16
__global__ void k_prep(P18 ps, const void* __restrict__ x, u16* __restrict__ xb,
                       float* __restrict__ prm, const int* __restrict__ flags){
  int b = blockIdx.x;
  int isbf = flags[1];
  if (b >= 390){
    long long i = (long long)(b - 390)*256 + threadIdx.x;
    xb[i] = f2bf(rdf(x, i, isbf));
    return;
  }
  int l = b / 130;
  int i = (b % 130)*256 + threadIdx.x;
  const void* Wl  = ps.p[6*l+0];
  const void* bl  = ps.p[6*l+1];
  const void* Wr  = ps.p[6*l+2];
  const void* br  = ps.p[6*l+3];
  const void* att = ps.p[6*l+4];
  const void* bb  = ps.p[6*l+5];
  float* p = prm + (size_t)l*PL;
  if (i < 32768){
    int n = i >> 7, k = i & 127;     // WT[n][k] = W[k][n]
    float v = (n < 128) ? rdf(Wl, k*128 + n, isbf) : rdf(Wr, k*128 + (n - 128), isbf);
    ((u16*)p)[i] = f2bf(v);          // 32768 u16 = 16384 floats
    return;
  }
  float* fb = p + 16384;
  if (i < 33024){ int gc = i - 32768; fb[gc] = (gc < 128) ? rdf(bl, gc, isbf) : rdf(br, gc - 128, isbf); }
  else if (i < 33152) fb[256 + (i - 33024)] = rdf(att, i - 33024, isbf);
  else                fb[384 + (i - 33152)] = rdf(bb, i - 33152, isbf);
}

// ---------- CSR build (by dst, self-loops appended); entry packs src|dst<<16 ----------
__global__ void k_hist(const void* __restrict__ ei, u32* __restrict__ cursor, const int* __restrict__ flags){
  int e = blockIdx.x*256 + threadIdx.x;
  if (e >= ET) return;
  int dd = (e < NE) ? geti(ei, (long long)NE + e, flags[0], NN) : e - NE;
  atomicAdd(&cursor[dd], 1u);
}

__global__ __launch_bounds__(256) void k_scanA(const u32* __restrict__ cursor, u32* __restrict__ psum){
  __shared__ u32 red[256];
  int t = threadIdx.x;
  red[t] = cursor[blockIdx.x*256 + t];
  __syncthreads();
  #pragma unroll
  for (int off = 128; off > 0; off >>= 1){
    if (t < off) red[t] += red[t + off];
    __syncthreads();
  }
  if (t == 0) psum[blockIdx.x] = red[0];
}

__global__ __launch_bounds__(256) void k_scanB(u32* __restrict__ psum, u32* __restrict__ offs,
                                               const void* __restrict__ batch, u32* __restrict__ bnd,
                                               const int* __restrict__ flags){
  __shared__ u32 sh[256];
  int t = threadIdx.x;
  sh[t] = (t < 160) ? psum[t] : 0u;
  __syncthreads();
  #pragma unroll
  for (int off = 1; off < 256; off <<= 1){
    u32 add = (t >= off) ? sh[t - off] : 0u;
    __syncthreads();
    sh[t] += add;
    __syncthreads();
  }
  if (t < 160) psum[t] = (t == 0) ? 0u : sh[t - 1];
  if (t == 160) offs[NN] = sh[159];
  if (t >= 192 && t <= 192 + NG){
    int g = t - 192;
    if (g == NG){ bnd[NG] = NN; }
    else {
      int f = flags[0];
      int lo = 0, hi = NN;
      while (lo < hi){
        int mid = (lo + hi) >> 1;
        if (geti(batch, mid, f, NG) < g) lo = mid + 1; else hi = mid;
      }
      bnd[g] = (u32)lo;
    }
  }
}

__global__ __launch_bounds__(256) void k_scanC(u32* __restrict__ cursor, u32* __restrict__ offs,
                                               const u32* __restrict__ psum){
  __shared__ u32 sh[256];
  int t = threadIdx.x;
  int gi = blockIdx.x*256 + t;
  u32 v = cursor[gi];
  sh[t] = v;
  __syncthreads();
  #pragma unroll
  for (int off = 1; off < 256; off <<= 1){
    u32 add = (t >= off) ? sh[t - off] : 0u;
    __syncthreads();
    sh[t] += add;
    __syncthreads();
  }
  u32 excl = ((t > 0) ? sh[t - 1] : 0u) + psum[blockIdx.x];
  offs[gi] = excl;
  cursor[gi] = excl;
}

__global__ void k_scatter(const void* __restrict__ ei, u32* __restrict__ cursor,
                          u32* __restrict__ csr, const int* __restrict__ flags){
  int e = blockIdx.x*256 + threadIdx.x;
  if (e >= ET) return;
  int f = flags[0];
  int s, dd;
  if (e < NE){ s = geti(ei, e, f, NN); dd = geti(ei, (long long)NE + e, f, NN); }
  else { s = dd = e - NE; }
  u32 pos = atomicAdd(&cursor[dd], 1u);
  csr[pos] = (u32)s | ((u32)dd << 16);
}

// ---------- GEMM via MFMA bf16: wave computes 16 rows x 4 col-tiles of 16 ----------
// A frag: 8 contiguous bf16 at X[row0+(l&15)][ (l>>4)*8 + kt*32 ]; B from pre-transposed
// WT[256][128] same pattern (B^T); C/D: col=lane&15, row=(lane>>4)*4+reg (HW-verified m89/m91).
__global__ __launch_bounds__(256) void k_gemm(const u16* __restrict__ Xb, const float* __restrict__ pr,
                                              u16* __restrict__ xl, u16* __restrict__ xr)
{
  int wv = threadIdx.x >> 6, lane = threadIdx.x & 63;
  int row0 = blockIdx.x*64 + wv*16;
  int rA = lane & 15, ks = lane >> 4;
  const u16* wt     = (const u16*)pr;
  const float* bias = pr + 16384;

  const u16* xp = Xb + (size_t)(row0 + rA)*D + ks*8;
  bf8v a0 = *(const bf8v*)(xp);
  bf8v a1 = *(const bf8v*)(xp + 32);
  bf8v a2 = *(const bf8v*)(xp + 64);
  bf8v a3 = *(const bf8v*)(xp + 96);

  int n0 = blockIdx.y*4;
  #pragma unroll
  for (int t = 0; t < 4; ++t, ++n0){
    int gc = n0*16 + rA;
    const u16* wp = wt + (size_t)gc*D + ks*8;
    bf8v b0 = *(const bf8v*)(wp);
    bf8v b1 = *(const bf8v*)(wp + 32);
    bf8v b2 = *(const bf8v*)(wp + 64);
    bf8v b3 = *(const bf8v*)(wp + 96);
    float bv = bias[gc];
    f4v acc = {bv, bv, bv, bv};
    acc = __builtin_amdgcn_mfma_f32_16x16x32_bf16(a0, b0, acc, 0, 0, 0);
    acc = __builtin_amdgcn_mfma_f32_16x16x32_bf16(a1, b1, acc, 0, 0, 0);
    acc = __builtin_amdgcn_mfma_f32_16x16x32_bf16(a2, b2, acc, 0, 0, 0);
    acc = __builtin_amdgcn_mfma_f32_16x16x32_bf16(a3, b3, acc, 0, 0, 0);
    u16* dst = (gc < 128) ? xl : xr;
    int cc = (gc < 128) ? gc : gc - 128;
    #pragma unroll
    for (int r = 0; r < 4; ++r)
      dst[(size_t)(row0 + ks*4 + r)*D + cc] = f2bf(acc[r]);
  }
}

// ---------- fused per-node attention: bf16 gather, depth-2 pipeline, defer-max ----------
__global__ __launch_bounds__(256) void k_node(const u16* __restrict__ xl, const u16* __restrict__ xr,
    const u32* __restrict__ offs, const u32* __restrict__ csr, const float* __restrict__ pr,
    u16* __restrict__ hb, float* __restrict__ hf, void* __restrict__ out,
    const int* __restrict__ flags, int last)
{
  int node = blockIdx.x*4 + (threadIdx.x >> 6);
  int lane = threadIdx.x & 63;
  int half = lane >> 5;
  int c = (lane & 31) * 4;
  float4 xrv  = ldb4(xr + (size_t)node*D + c);
  float4 attv = *(const float4*)(pr + 16640 + c);
  u32 j0 = offs[node], j1 = offs[node + 1];

  float mx = -1e30f, ssum = 0.f;
  float4 acc = make_float4(0.f, 0.f, 0.f, 0.f);

  #define SRCJ(jj) ((int)(csr[(jj) < j1 ? (jj) : j0] & 0xFFFFu))
  u32 j = j0 + half;
  int s0 = SRCJ(j), s1 = SRCJ(j+2);
  float4 g0 = ldb4(xl + (size_t)s0*D + c);
  float4 g1 = ldb4(xl + (size_t)s1*D + c);
  int s2 = SRCJ(j+4), s3 = SRCJ(j+6);

  for (; j < j1; j += 4){
    float4 n0 = ldb4(xl + (size_t)s2*D + c);
    float4 n1 = ldb4(xl + (size_t)s3*D + c);
    int t0 = SRCJ(j+8), t1 = SRCJ(j+10);

    {
      float m, p;
      m = g0.x + xrv.x; p = fmaxf(m, 0.2f*m) * attv.x;
      m = g0.y + xrv.y; p = fmaf(fmaxf(m, 0.2f*m), attv.y, p);
      m = g0.z + xrv.z; p = fmaf(fmaxf(m, 0.2f*m), attv.z, p);
      m = g0.w + xrv.w; p = fmaf(fmaxf(m, 0.2f*m), attv.w, p);
      p += __shfl_xor(p, 1, 64);
      p += __shfl_xor(p, 2, 64);
      p += __shfl_xor(p, 4, 64);
      if (p > mx + 8.f){
        float eo = __expf(mx - p);
        ssum  *= eo;
        acc.x *= eo; acc.y *= eo; acc.z *= eo; acc.w *= eo;
        mx = p;
      }
      float en = __expf(p - mx);
      ssum += en;
      acc.x = fmaf(en, g0.x, acc.x);
      acc.y = fmaf(en, g0.y, acc.y);
      acc.z = fmaf(en, g0.z, acc.z);
      acc.w = fmaf(en, g0.w, acc.w);
    }
    if (j + 2 < j1){
      float m, p;
      m = g1.x + xrv.x; p = fmaxf(m, 0.2f*m) * attv.x;
      m = g1.y + xrv.y; p = fmaf(fmaxf(m, 0.2f*m), attv.y, p);
      m = g1.z + xrv.z; p = fmaf(fmaxf(m, 0.2f*m), attv.z, p);
      m = g1.w + xrv.w; p = fmaf(fmaxf(m, 0.2f*m), attv.w, p);
      p += __shfl_xor(p, 1, 64);
      p += __shfl_xor(p, 2, 64);
      p += __shfl_xor(p, 4, 64);
      if (p > mx + 8.f){
        float eo = __expf(mx - p);
        ssum  *= eo;
        acc.x *= eo; acc.y *= eo; acc.z *= eo; acc.w *= eo;
        mx = p;
      }
      float en = __expf(p - mx);
      ssum += en;
      acc.x = fmaf(en, g1.x, acc.x);
      acc.y = fmaf(en, g1.y, acc.y);
      acc.z = fmaf(en, g1.z, acc.z);
      acc.w = fmaf(en, g1.w, acc.w);
    }
    g0 = n0; g1 = n1; s2 = t0; s3 = t1;
  }
  #undef SRCJ

  float mo = __shfl_xor(mx, 32, 64);
  float so = __shfl_xor(ssum, 32, 64);
  float ax = __shfl_xor(acc.x, 32, 64);
  float ay = __shfl_xor(acc.y, 32, 64);
  float az = __shfl_xor(acc.z, 32, 64);
  float aw = __shfl_xor(acc.w, 32, 64);
  float n  = fmaxf(mx, mo);
  float e0 = __expf(mx - n), e1 = __expf(mo - n);
  ssum  = ssum*e0 + so*e1;
  acc.x = acc.x*e0 + ax*e1;
  acc.y = acc.y*e0 + ay*e1;
  acc.z = acc.z*e0 + az*e1;
  acc.w = acc.w*e0 + aw*e1;

  if (half == 0){
    float inv = 1.0f / fmaxf(ssum, 1e-30f);
    float4 bv = *(const float4*)(pr + 16768 + c);
    float4 v = make_float4(acc.x*inv + bv.x, acc.y*inv + bv.y,
                           acc.z*inv + bv.z, acc.w*inv + bv.w);
    if (!last){
      v.x = fmaxf(v.x, 0.f); v.y = fmaxf(v.y, 0.f);
      v.z = fmaxf(v.z, 0.f); v.w = fmaxf(v.w, 0.f);
      ushort4 o = make_ushort4(f2bf(v.x), f2bf(v.y), f2bf(v.z), f2bf(v.w));
      *(ushort4*)(hb + (size_t)node*D + c) = o;     // bf16 h for next layer's MFMA gemm
    } else {
      *(float4*)(hf + (size_t)node*D + c) = v;      // f32 h for pooling
      int isbf = flags[1];
      long long o = (long long)NG*D + (long long)node*D + c;
      stf(out, o+0, v.x, isbf); stf(out, o+1, v.y, isbf);
      stf(out, o+2, v.z, isbf); stf(out, o+3, v.w, isbf);
    }
  }
}

// ---------- two-stage mean pool ----------
__global__ __launch_bounds__(256) void k_pool1(const float* __restrict__ h, const u32* __restrict__ bnd,
                                               float* __restrict__ pool){
  int g = blockIdx.x >> 6, sl = blockIdx.x & 63;
  int ch = threadIdx.x & 127, ro = threadIdx.x >> 7;
  u32 b0 = bnd[g], b1 = bnd[g + 1];
  float acc = 0.f;
  for (u32 r = b0 + sl*2 + ro; r < b1; r += 128) acc += h[(size_t)r*D + ch];
  unsafeAtomicAdd(&pool[g*D + ch], acc);
}

__global__ void k_pool2(const float* __restrict__ pool, const u32* __restrict__ bnd,
                        void* __restrict__ out, const int* __restrict__ flags){
  int i = blockIdx.x*256 + threadIdx.x;
  if (i >= NG*D) return;
  int g = i >> 7;
  float c = (float)(bnd[g + 1] - bnd[g]);
  stf(out, i, pool[i] / fmaxf(c, 1.f), flags[1]);
}

extern "C" void kernel_launch(void* const* d_in, const int* in_sizes, int n_in,
                              void* d_out, int out_size, void* d_ws, size_t ws_size,
                              hipStream_t stream) {
  const void* x     = d_in[0];
  const void* ei    = d_in[1];
  const void* batch = d_in[2];

  const long long nf = (long long)NN*D + 3*PL + NG*D;          // f32 section
  const long long nh = (long long)NN*D*3;                      // u16 section (xb,xl,xr)
  const long long nu = (NN + 1) + NN + ET + (NG + 1) + 2 + 160;
  if (ws_size < (size_t)nf*4 + (size_t)nh*2 + (size_t)nu*4 + 256) return;

  float* ws    = (float*)d_ws;
  float* xf    = ws;                               // NN*D f32 (last-layer h for pooling)
  u16*  xb    = (u16*)(xf + (size_t)NN*D);         // NN*D bf16 (gemm input / h buffer)
  u16*  xl    = xb + (size_t)NN*D;                 // NN*D bf16
  u16*  xr    = xl + (size_t)NN*D;                 // NN*D bf16
  float* prm   = (float*)(xr + (size_t)NN*D);      // 3*PL f32 (WT bf16 packed inside)
  float* pool  = prm + 3*PL;                       // NG*D
  u32*  offs   = (u32*)(pool + NG*D);              // NN+1
  u32*  cursor = offs + (NN + 1);                  // NN
  u32*  csr    = cursor + NN;                      // ET
  u32*  bnd    = csr + ET;                         // NG+1
  u32*  psum   = bnd + (NG + 1);                   // 160
  int*  flags  = (int*)(psum + 160);               // 2

  k_setup<<<169, 256, 0, stream>>>(ei, x, flags, cursor, pool);
  P18 ps;
  for (int i = 0; i < 18; ++i) ps.p[i] = d_in[3 + i];
  k_prep<<<390 + (NN*D)/256, 256, 0, stream>>>(ps, x, xb, prm, flags);

  k_hist<<<ET/256, 256, 0, stream>>>(ei, cursor, flags);
  k_scanA<<<160, 256, 0, stream>>>(cursor, psum);
  k_scanB<<<1, 256, 0, stream>>>(psum, offs, batch, bnd, flags);
  k_scanC<<<160, 256, 0, stream>>>(cursor, offs, psum);
  k_scatter<<<ET/256, 256, 0, stream>>>(ei, cursor, csr, flags);

  for (int l = 0; l < 3; ++l){
    const float* p = prm + (size_t)l*PL;
    k_gemm<<<dim3(NN/64, 4), 256, 0, stream>>>(xb, p, xl, xr);
    k_node<<<NN/4, 256, 0, stream>>>(xl, xr, offs, csr, p, xb, xf, d_out, flags, l == 2);
  }
  k_pool1<<<NG*64, 256, 0, stream>>>(xf, bnd, pool);
  k_pool2<<<8, 256, 0, stream>>>(pool, bnd, d_out, flags);
}